// Round 6
// baseline (2690.984 us; speedup 1.0000x reference)
//
#include <hip/hip_runtime.h>
#include <hip/hip_bf16.h>
#include <float.h>

#define NPT    4096
#define EMB    512
#define NH     8
#define HD     64
#define KSPLIT 32     // score k-range split: KRANGE = 128

typedef __attribute__((ext_vector_type(8))) short bf16x8;
typedef __attribute__((ext_vector_type(4))) float f32x4;

// product schedule for exact-f32 via 3-plane bf16: (A-plane, B-plane)
// hh first, then 2^-8 terms, then 2^-16 terms
__device__ __constant__ const int PPA[6] = {0, 0, 1, 0, 2, 1};
__device__ __constant__ const int PPB[6] = {0, 1, 0, 2, 0, 1};

// ---------------------------------------------------------------------------
// 1) pack adj (int32 0/1, [N][N]) into bitmask [N][N/32]
// ---------------------------------------------------------------------------
__global__ __launch_bounds__(256) void pack_adj_kernel(const int* __restrict__ adj,
                                                       unsigned* __restrict__ bits) {
    int gid = blockIdx.x * 256 + threadIdx.x;
    int q = gid >> 7;
    int w = gid & 127;
    const int4* p = (const int4*)(adj + (size_t)q * NPT + w * 32);
    unsigned m = 0;
#pragma unroll
    for (int i = 0; i < 8; ++i) {
        int4 v = p[i];
        m |= (v.x != 0 ? 1u : 0u) << (i * 4 + 0);
        m |= (v.y != 0 ? 1u : 0u) << (i * 4 + 1);
        m |= (v.z != 0 ? 1u : 0u) << (i * 4 + 2);
        m |= (v.w != 0 ? 1u : 0u) << (i * 4 + 3);
    }
    bits[gid] = m;
}

// ---------------------------------------------------------------------------
// helper: exact 3-way bf16 split of an f32 (hi+mid+lo covers all 24 bits)
// ---------------------------------------------------------------------------
__device__ __forceinline__ void split3(float a, unsigned short& h,
                                       unsigned short& m, unsigned short& l) {
    __hip_bfloat16 bh = __float2bfloat16(a);
    float fh = __bfloat162float(bh);
    float r1 = a - fh;
    __hip_bfloat16 bm = __float2bfloat16(r1);
    float fm = __bfloat162float(bm);
    float r2 = r1 - fm;
    __hip_bfloat16 bl = __float2bfloat16(r2);
    h = *reinterpret_cast<unsigned short*>(&bh);
    m = *reinterpret_cast<unsigned short*>(&bm);
    l = *reinterpret_cast<unsigned short*>(&bl);
}

// ---------------------------------------------------------------------------
// 2) elementwise: split x, WQ, WK, WV into 3 bf16 planes each (K-major kept)
// ---------------------------------------------------------------------------
__global__ __launch_bounds__(256) void split_planes(const float* __restrict__ x,
                                                    const float* __restrict__ wq,
                                                    const float* __restrict__ wk,
                                                    const float* __restrict__ wv,
                                                    unsigned short* __restrict__ xs,
                                                    unsigned short* __restrict__ wqs,
                                                    unsigned short* __restrict__ wks,
                                                    unsigned short* __restrict__ wvs) {
    const float* src; unsigned short* dst; size_t n4, PL;
    int y = blockIdx.y;
    if (y == 0)      { src = x;  dst = xs;  PL = (size_t)NPT * EMB; }
    else if (y == 1) { src = wq; dst = wqs; PL = (size_t)EMB * EMB; }
    else if (y == 2) { src = wk; dst = wks; PL = (size_t)EMB * EMB; }
    else             { src = wv; dst = wvs; PL = (size_t)EMB * EMB; }
    n4 = PL / 4;
    size_t i = (size_t)blockIdx.x * 256 + threadIdx.x;
    if (i >= n4) return;
    float4 v = ((const float4*)src)[i];
    ushort4 h, m, l;
    split3(v.x, h.x, m.x, l.x);
    split3(v.y, h.y, m.y, l.y);
    split3(v.z, h.z, m.z, l.z);
    split3(v.w, h.w, m.w, l.w);
    ((ushort4*)dst)[i]            = h;
    ((ushort4*)(dst + PL))[i]     = m;
    ((ushort4*)(dst + 2 * PL))[i] = l;
}

// ---------------------------------------------------------------------------
// 3) projections via split-bf16 MFMA, LDS-staged W tile (shared by 4 waves),
//    reg-double-buffered x fragments. D[e][n] = sum_k W[e][k] x[n][k].
//    Block 64e x 128n, wave wv owns n-range wv*32 (nt=2, mt=4).
//    z=0 -> Q3 planes [3][NH][NPT][HD]; z=1 -> K3; z=2 -> V f32 [n][e].
// ---------------------------------------------------------------------------
__global__ __launch_bounds__(256, 2) void gemm_mfma(const unsigned short* __restrict__ xs,
                                                    const unsigned short* __restrict__ wqs,
                                                    const unsigned short* __restrict__ wks,
                                                    const unsigned short* __restrict__ wvs,
                                                    unsigned short* __restrict__ Q3,
                                                    unsigned short* __restrict__ K3,
                                                    float* __restrict__ V) {
    const int z = blockIdx.z;
    const unsigned short* W3 = (z == 0) ? wqs : (z == 1) ? wks : wvs;
    unsigned short* O3 = (z == 0) ? Q3 : K3;
    const size_t XPL = (size_t)NPT * EMB;
    const size_t WPL = (size_t)EMB * EMB;
    const size_t OPL = (size_t)NH * NPT * HD;

    const int nb = blockIdx.x * 128;
    const int eb = blockIdx.y * 64;
    const int tid = threadIdx.x;
    const int lane = tid & 63;
    const int m = lane & 15, quad = lane >> 4;
    const int n0 = nb + (tid >> 6) * 32;

    __shared__ unsigned short Ws[2][3][64][36];   // 32 data + 4 pad per e-row

    const int se = tid >> 2, sh = (tid & 3) * 8;  // staging coords
    int4 sreg[3];

    auto load_w = [&](int kc) {
#pragma unroll
        for (int p = 0; p < 3; ++p)
            sreg[p] = *(const int4*)(W3 + (size_t)p * WPL + (size_t)(eb + se) * EMB + kc * 32 + sh);
    };
    auto write_w = [&](int buf) {
#pragma unroll
        for (int p = 0; p < 3; ++p)
            *(int4*)&Ws[buf][p][se][sh] = sreg[p];
    };

    bf16x8 bfA[2][3], bfB[2][3];
    auto load_x = [&](bf16x8 (&dst)[2][3], int kc) {
#pragma unroll
        for (int nt = 0; nt < 2; ++nt)
#pragma unroll
            for (int p = 0; p < 3; ++p)
                dst[nt][p] = *(const bf16x8*)(xs + (size_t)p * XPL
                    + (size_t)(n0 + nt * 16 + m) * EMB + kc * 32 + quad * 8);
    };

    f32x4 acc[4][2];
#pragma unroll
    for (int mt = 0; mt < 4; ++mt)
#pragma unroll
        for (int nt = 0; nt < 2; ++nt) acc[mt][nt] = (f32x4){0.f, 0.f, 0.f, 0.f};

    // prologue: stage tile 0 into buf 0, x frags for kc=0
    load_w(0); write_w(0);
    load_x(bfA, 0);

    auto body = [&](int kc, bf16x8 (&bc)[2][3], bf16x8 (&bn)[2][3]) {
        __syncthreads();                       // buf[kc&1] visible to all waves
        bf16x8 af[4][3];
#pragma unroll
        for (int mt = 0; mt < 4; ++mt)
#pragma unroll
            for (int p = 0; p < 3; ++p)
                af[mt][p] = *(const bf16x8*)&Ws[kc & 1][p][mt * 16 + m][quad * 8];
        if (kc < 15) { load_w(kc + 1); load_x(bn, kc + 1); }   // issue early
#pragma unroll
        for (int pp = 0; pp < 6; ++pp)
#pragma unroll
            for (int mt = 0; mt < 4; ++mt)
#pragma unroll
                for (int nt = 0; nt < 2; ++nt)
                    acc[mt][nt] = __builtin_amdgcn_mfma_f32_16x16x32_bf16(
                        af[mt][PPA[pp]], bc[nt][PPB[pp]], acc[mt][nt], 0, 0, 0);
        if (kc < 15) write_w((kc & 1) ^ 1);    // waits for load_w; had whole burst
    };

#pragma unroll 1
    for (int kc2 = 0; kc2 < 16; kc2 += 2) {
        body(kc2, bfA, bfB);
        body(kc2 + 1, bfB, bfA);
    }

    // C/D: col(lane&15)=n, row(quad*4+r)=e -> regs are consecutive e/d
#pragma unroll
    for (int mt = 0; mt < 4; ++mt)
#pragma unroll
        for (int nt = 0; nt < 2; ++nt) {
            const int n = n0 + nt * 16 + m;
            const int d0 = mt * 16 + quad * 4;
            f32x4 a = acc[mt][nt];
            if (z == 2) {
                *(f32x4*)(V + (size_t)n * EMB + eb + d0) = a;
            } else {
                const int h = eb >> 6;
                ushort4 ph, pm, pl;
                split3(a[0], ph.x, pm.x, pl.x);
                split3(a[1], ph.y, pm.y, pl.y);
                split3(a[2], ph.z, pm.z, pl.z);
                split3(a[3], ph.w, pm.w, pl.w);
                size_t base = ((size_t)h * NPT + n) * HD + d0;
                *(ushort4*)(O3 + base)           = ph;
                *(ushort4*)(O3 + OPL + base)     = pm;
                *(ushort4*)(O3 + 2 * OPL + base) = pl;
            }
        }
}

// ---------------------------------------------------------------------------
// 4) masked argmax via bf16x3 MFMA. K tiles (32k x 64d x 3p = 12 KB) LDS
//    double-buffered, prefetch issued before the MFMA burst. Q fragments
//    persistent in regs per head. A = K (m=k), B = Q (n=q).
//    Block: 4 waves x 64q = 256q; k-range 128 per block.
// ---------------------------------------------------------------------------
__global__ __launch_bounds__(256, 2) void score_mfma(const unsigned short* __restrict__ Q3,
                                                     const unsigned short* __restrict__ K3,
                                                     const unsigned* __restrict__ bits,
                                                     float* __restrict__ pval,
                                                     int* __restrict__ pidx) {
    const int qb  = blockIdx.x * 256;        // x = q (consecutive blocks share K slice)
    const int ks  = blockIdx.y;              // 0..KSPLIT-1, KRANGE=128
    const int tid = threadIdx.x;
    const int lane = tid & 63;
    const int m    = lane & 15;
    const int quad = lane >> 4;
    const size_t PL = (size_t)NH * NPT * HD;
    const int kq = qb + (tid >> 6) * 64;

    __shared__ unsigned short Ks[2][3][32][72];   // 64 data + 8 pad per k-row

    const int sk = tid >> 3, sh = (tid & 7) * 8;  // staging coords
    int4 sreg[3];
    auto load_tile = [&](int h, int kst) {
#pragma unroll
        for (int p = 0; p < 3; ++p)
            sreg[p] = *(const int4*)(K3 + (size_t)p * PL
                + ((size_t)h * NPT + ks * 128 + kst * 32 + sk) * HD + sh);
    };
    auto write_tile = [&](int buf) {
#pragma unroll
        for (int p = 0; p < 3; ++p)
            *(int4*)&Ks[buf][p][sk][sh] = sreg[p];
    };

    load_tile(0, 0); write_tile(0);          // prologue: tile (h0,kst0) -> buf 0

#pragma unroll 1
    for (int h = 0; h < NH; ++h) {
        // persistent Q fragments (B-layout: n=lane&15, k=quad*8+j)
        bf16x8 qf[4][2][3];
#pragma unroll
        for (int nt = 0; nt < 4; ++nt)
#pragma unroll
            for (int dc = 0; dc < 2; ++dc)
#pragma unroll
                for (int p = 0; p < 3; ++p)
                    qf[nt][dc][p] = *(const bf16x8*)(Q3 + (size_t)p * PL
                        + ((size_t)h * NPT + kq + nt * 16 + m) * HD + dc * 32 + quad * 8);

        float bestv[4]; int besti[4];
#pragma unroll
        for (int nt = 0; nt < 4; ++nt) { bestv[nt] = -FLT_MAX; besti[nt] = 0; }

#pragma unroll
        for (int kst = 0; kst < 4; ++kst) {
            const int buf = kst & 1;
            const int kbase = ks * 128 + kst * 32;
            const bool last = (h == NH - 1) && (kst == 3);

            __syncthreads();                 // buf now staged & visible

            // current-tile fragments from LDS
            bf16x8 kf[2][2][3];
#pragma unroll
            for (int mt = 0; mt < 2; ++mt)
#pragma unroll
                for (int dc = 0; dc < 2; ++dc)
#pragma unroll
                    for (int p = 0; p < 3; ++p)
                        kf[mt][dc][p] = *(const bf16x8*)
                            &Ks[buf][p][mt * 16 + m][dc * 32 + quad * 8];

            // issue next tile's global loads EARLY (land during MFMA burst)
            if (!last) load_tile(kst < 3 ? h : h + 1, (kst + 1) & 3);

            // bits words for this kst (issued before MFMAs, used after)
            unsigned bw[4];
#pragma unroll
            for (int nt = 0; nt < 4; ++nt)
                bw[nt] = bits[(size_t)(kq + nt * 16 + m) * (NPT / 32) + (kbase >> 5)];

            // MFMA burst, product-major (8 independent acc chains)
            f32x4 acc[2][4];
#pragma unroll
            for (int mt = 0; mt < 2; ++mt)
#pragma unroll
                for (int nt = 0; nt < 4; ++nt) acc[mt][nt] = (f32x4){0.f, 0.f, 0.f, 0.f};
#pragma unroll
            for (int pp = 0; pp < 6; ++pp)
#pragma unroll
                for (int dc = 0; dc < 2; ++dc)
#pragma unroll
                    for (int mt = 0; mt < 2; ++mt)
#pragma unroll
                        for (int nt = 0; nt < 4; ++nt)
                            acc[mt][nt] = __builtin_amdgcn_mfma_f32_16x16x32_bf16(
                                kf[mt][dc][PPA[pp]], qf[nt][dc][PPB[pp]], acc[mt][nt], 0, 0, 0);

            // epilogue: C col=lane&15 -> q; row=quad*4+r -> k
#pragma unroll
            for (int nt = 0; nt < 4; ++nt) {
                unsigned w = bw[nt];
#pragma unroll
                for (int mt = 0; mt < 2; ++mt) {
                    int k0 = mt * 16 + quad * 4;
                    f32x4 a = acc[mt][nt];
#pragma unroll
                    for (int r = 0; r < 4; ++r) {
                        if ((w >> (k0 + r)) & 1u) {
                            float s = a[r];
                            if (s > bestv[nt]) { bestv[nt] = s; besti[nt] = kbase + k0 + r; }
                        }
                    }
                }
            }

            // stage next tile into the other buffer (loads had the whole burst)
            if (!last) write_tile(buf ^ 1);
        }

        // reduce across quad groups; smaller idx on tie
#pragma unroll
        for (int nt = 0; nt < 4; ++nt) {
            float v = bestv[nt]; int bi = besti[nt];
#pragma unroll
            for (int off = 16; off < 64; off <<= 1) {
                float ov = __shfl_xor(v, off);
                int   oi = __shfl_xor(bi, off);
                if (ov > v || (ov == v && oi < bi)) { v = ov; bi = oi; }
            }
            if (quad == 0) {
                size_t o = ((size_t)h * KSPLIT + ks) * NPT + kq + nt * 16 + m;
                pval[o] = v; pidx[o] = bi;
            }
        }
    }
}

// ---------------------------------------------------------------------------
// 5) reduce k-split partials, gather winner V row * (1/NH)
// ---------------------------------------------------------------------------
__global__ __launch_bounds__(128) void gather_out(const float* __restrict__ V,
                                                  const float* __restrict__ pval,
                                                  const int* __restrict__ pidx,
                                                  float* __restrict__ out) {
    const int q = blockIdx.x;
    const int tid = threadIdx.x;
    __shared__ int widx[NH];
    if (tid < NH) {
        float bv = -FLT_MAX; int bi = 0;
        for (int ks = 0; ks < KSPLIT; ++ks) {
            size_t off = ((size_t)tid * KSPLIT + ks) * NPT + q;
            float v = pval[off];
            if (v > bv) { bv = v; bi = pidx[off]; }
        }
        widx[tid] = bi;
    }
    __syncthreads();
    const int h = tid >> 4;
    const int d4 = (tid & 15) * 4;
    const int k = widx[h];
    float4 v = *(const float4*)(V + (size_t)k * EMB + h * HD + d4);
    v.x *= 0.125f; v.y *= 0.125f; v.z *= 0.125f; v.w *= 0.125f;
    *(float4*)(out + (size_t)q * EMB + h * HD + d4) = v;
}

// ---------------------------------------------------------------------------
extern "C" void kernel_launch(void* const* d_in, const int* in_sizes, int n_in,
                              void* d_out, int out_size, void* d_ws, size_t ws_size,
                              hipStream_t stream) {
    const float* x   = (const float*)d_in[0];
    const int*   adj = (const int*)d_in[1];
    const float* WQ  = (const float*)d_in[2];
    const float* WK  = (const float*)d_in[3];
    const float* WV  = (const float*)d_in[4];
    // we/be are dead: energy is constant along k -> argmax unchanged.
    float* out = (float*)d_out;

    char* ws = (char*)d_ws;
    const size_t MB = 1u << 20;
    unsigned short* xs   = (unsigned short*)(ws);                      // 12 MB (dead after gemm)
    unsigned short* wqs  = (unsigned short*)(ws + 12 * MB);            // 1.5 MB
    unsigned short* wks  = (unsigned short*)(ws + 13 * MB + 512 * 1024);
    unsigned short* wvs  = (unsigned short*)(ws + 15 * MB);
    unsigned short* Q3   = (unsigned short*)(ws + 17 * MB);            // 12 MB [3][8][4096][64]
    unsigned short* K3   = (unsigned short*)(ws + 29 * MB);            // 12 MB
    float*          V    = (float*)(ws + 41 * MB);                     // 8 MB [4096][512]
    unsigned*       bits = (unsigned*)(ws + 49 * MB);                  // 2 MB
    float*          pval = (float*)(ws);                               // 4 MB, aliases dead xs
    int*            pidx = (int*)(ws + 4 * MB);                        // 4 MB, aliases dead xs

    pack_adj_kernel<<<dim3(NPT * 128 / 256), dim3(256), 0, stream>>>(adj, bits);
    split_planes<<<dim3(2048, 4), dim3(256), 0, stream>>>(x, WQ, WK, WV, xs, wqs, wks, wvs);
    gemm_mfma<<<dim3(NPT / 128, EMB / 64, 3), dim3(256), 0, stream>>>(xs, wqs, wks, wvs, Q3, K3, V);
    score_mfma<<<dim3(NPT / 256, KSPLIT), dim3(256), 0, stream>>>(Q3, K3, bits, pval, pidx);
    gather_out<<<dim3(NPT), dim3(128), 0, stream>>>(V, pval, pidx, out);
}

// Round 7
// 398.008 us; speedup vs baseline: 6.7611x; 6.7611x over previous
//
#include <hip/hip_runtime.h>
#include <hip/hip_bf16.h>
#include <float.h>

#define NPT    4096
#define EMB    512
#define NH     8
#define HD     64
#define KSPLIT 32     // score k-range split: KRANGE = 128

typedef __attribute__((ext_vector_type(8))) short bf16x8;
typedef __attribute__((ext_vector_type(4))) float f32x4;

// product schedule for exact-f32 via 3-plane bf16: (A-plane, B-plane).
// constexpr at file scope: folds at compile time under full unroll, so
// fragment-array indices stay compile-time constants (NOT __constant__
// memory -- that forced the arrays to scratch in R6: 704 MB WRITE_SIZE).
constexpr int PPA[6] = {0, 0, 1, 0, 2, 1};
constexpr int PPB[6] = {0, 1, 0, 2, 0, 1};

// ---------------------------------------------------------------------------
// 1) pack adj (int32 0/1, [N][N]) into bitmask [N][N/32]
// ---------------------------------------------------------------------------
__global__ __launch_bounds__(256) void pack_adj_kernel(const int* __restrict__ adj,
                                                       unsigned* __restrict__ bits) {
    int gid = blockIdx.x * 256 + threadIdx.x;
    int q = gid >> 7;
    int w = gid & 127;
    const int4* p = (const int4*)(adj + (size_t)q * NPT + w * 32);
    unsigned m = 0;
#pragma unroll
    for (int i = 0; i < 8; ++i) {
        int4 v = p[i];
        m |= (v.x != 0 ? 1u : 0u) << (i * 4 + 0);
        m |= (v.y != 0 ? 1u : 0u) << (i * 4 + 1);
        m |= (v.z != 0 ? 1u : 0u) << (i * 4 + 2);
        m |= (v.w != 0 ? 1u : 0u) << (i * 4 + 3);
    }
    bits[gid] = m;
}

// ---------------------------------------------------------------------------
// helper: exact 3-way bf16 split of an f32 (hi+mid+lo covers all 24 bits)
// ---------------------------------------------------------------------------
__device__ __forceinline__ void split3(float a, unsigned short& h,
                                       unsigned short& m, unsigned short& l) {
    __hip_bfloat16 bh = __float2bfloat16(a);
    float fh = __bfloat162float(bh);
    float r1 = a - fh;
    __hip_bfloat16 bm = __float2bfloat16(r1);
    float fm = __bfloat162float(bm);
    float r2 = r1 - fm;
    __hip_bfloat16 bl = __float2bfloat16(r2);
    h = *reinterpret_cast<unsigned short*>(&bh);
    m = *reinterpret_cast<unsigned short*>(&bm);
    l = *reinterpret_cast<unsigned short*>(&bl);
}

// ---------------------------------------------------------------------------
// 2) elementwise: split x, WQ, WK, WV into 3 bf16 planes each (K-major kept)
// ---------------------------------------------------------------------------
__global__ __launch_bounds__(256) void split_planes(const float* __restrict__ x,
                                                    const float* __restrict__ wq,
                                                    const float* __restrict__ wk,
                                                    const float* __restrict__ wv,
                                                    unsigned short* __restrict__ xs,
                                                    unsigned short* __restrict__ wqs,
                                                    unsigned short* __restrict__ wks,
                                                    unsigned short* __restrict__ wvs) {
    const float* src; unsigned short* dst; size_t n4, PL;
    int y = blockIdx.y;
    if (y == 0)      { src = x;  dst = xs;  PL = (size_t)NPT * EMB; }
    else if (y == 1) { src = wq; dst = wqs; PL = (size_t)EMB * EMB; }
    else if (y == 2) { src = wk; dst = wks; PL = (size_t)EMB * EMB; }
    else             { src = wv; dst = wvs; PL = (size_t)EMB * EMB; }
    n4 = PL / 4;
    size_t i = (size_t)blockIdx.x * 256 + threadIdx.x;
    if (i >= n4) return;
    float4 v = ((const float4*)src)[i];
    ushort4 h, m, l;
    split3(v.x, h.x, m.x, l.x);
    split3(v.y, h.y, m.y, l.y);
    split3(v.z, h.z, m.z, l.z);
    split3(v.w, h.w, m.w, l.w);
    ((ushort4*)dst)[i]            = h;
    ((ushort4*)(dst + PL))[i]     = m;
    ((ushort4*)(dst + 2 * PL))[i] = l;
}

// ---------------------------------------------------------------------------
// 3) projections via split-bf16 MFMA, LDS-staged W tile (shared by 4 waves),
//    reg-double-buffered x fragments. D[e][n] = sum_k W[e][k] x[n][k].
//    Block 64e x 128n, wave wv owns n-range wv*32 (nt=2, mt=4).
//    z=0 -> Q3 planes [3][NH][NPT][HD]; z=1 -> K3; z=2 -> V f32 [n][e].
// ---------------------------------------------------------------------------
__global__ __launch_bounds__(256, 2) void gemm_mfma(const unsigned short* __restrict__ xs,
                                                    const unsigned short* __restrict__ wqs,
                                                    const unsigned short* __restrict__ wks,
                                                    const unsigned short* __restrict__ wvs,
                                                    unsigned short* __restrict__ Q3,
                                                    unsigned short* __restrict__ K3,
                                                    float* __restrict__ V) {
    const int z = blockIdx.z;
    const unsigned short* W3 = (z == 0) ? wqs : (z == 1) ? wks : wvs;
    unsigned short* O3 = (z == 0) ? Q3 : K3;
    const size_t XPL = (size_t)NPT * EMB;
    const size_t WPL = (size_t)EMB * EMB;
    const size_t OPL = (size_t)NH * NPT * HD;

    const int nb = blockIdx.x * 128;
    const int eb = blockIdx.y * 64;
    const int tid = threadIdx.x;
    const int lane = tid & 63;
    const int m = lane & 15, quad = lane >> 4;
    const int n0 = nb + (tid >> 6) * 32;

    __shared__ unsigned short Ws[2][3][64][36];   // 32 data + 4 pad per e-row

    const int se = tid >> 2, sh = (tid & 3) * 8;  // staging coords
    int4 sreg[3];

    auto load_w = [&](int kc) {
#pragma unroll
        for (int p = 0; p < 3; ++p)
            sreg[p] = *(const int4*)(W3 + (size_t)p * WPL + (size_t)(eb + se) * EMB + kc * 32 + sh);
    };
    auto write_w = [&](int buf) {
#pragma unroll
        for (int p = 0; p < 3; ++p)
            *(int4*)&Ws[buf][p][se][sh] = sreg[p];
    };

    bf16x8 bfA[2][3], bfB[2][3];
    auto load_x = [&](bf16x8 (&dst)[2][3], int kc) {
#pragma unroll
        for (int nt = 0; nt < 2; ++nt)
#pragma unroll
            for (int p = 0; p < 3; ++p)
                dst[nt][p] = *(const bf16x8*)(xs + (size_t)p * XPL
                    + (size_t)(n0 + nt * 16 + m) * EMB + kc * 32 + quad * 8);
    };

    f32x4 acc[4][2];
#pragma unroll
    for (int mt = 0; mt < 4; ++mt)
#pragma unroll
        for (int nt = 0; nt < 2; ++nt) acc[mt][nt] = (f32x4){0.f, 0.f, 0.f, 0.f};

    // prologue: stage tile 0 into buf 0, x frags for kc=0
    load_w(0); write_w(0);
    load_x(bfA, 0);

    auto body = [&](int kc, bf16x8 (&bc)[2][3], bf16x8 (&bn)[2][3]) {
        __syncthreads();                       // buf[kc&1] visible to all waves
        bf16x8 af[4][3];
#pragma unroll
        for (int mt = 0; mt < 4; ++mt)
#pragma unroll
            for (int p = 0; p < 3; ++p)
                af[mt][p] = *(const bf16x8*)&Ws[kc & 1][p][mt * 16 + m][quad * 8];
        if (kc < 15) { load_w(kc + 1); load_x(bn, kc + 1); }   // issue early
#pragma unroll
        for (int pp = 0; pp < 6; ++pp)
#pragma unroll
            for (int mt = 0; mt < 4; ++mt)
#pragma unroll
                for (int nt = 0; nt < 2; ++nt)
                    acc[mt][nt] = __builtin_amdgcn_mfma_f32_16x16x32_bf16(
                        af[mt][PPA[pp]], bc[nt][PPB[pp]], acc[mt][nt], 0, 0, 0);
        if (kc < 15) write_w((kc & 1) ^ 1);    // waits for load_w; had whole burst
    };

#pragma unroll 1
    for (int kc2 = 0; kc2 < 16; kc2 += 2) {
        body(kc2, bfA, bfB);
        body(kc2 + 1, bfB, bfA);
    }

    // C/D: col(lane&15)=n, row(quad*4+r)=e -> regs are consecutive e/d
#pragma unroll
    for (int mt = 0; mt < 4; ++mt)
#pragma unroll
        for (int nt = 0; nt < 2; ++nt) {
            const int n = n0 + nt * 16 + m;
            const int d0 = mt * 16 + quad * 4;
            f32x4 a = acc[mt][nt];
            if (z == 2) {
                *(f32x4*)(V + (size_t)n * EMB + eb + d0) = a;
            } else {
                const int h = eb >> 6;
                ushort4 ph, pm, pl;
                split3(a[0], ph.x, pm.x, pl.x);
                split3(a[1], ph.y, pm.y, pl.y);
                split3(a[2], ph.z, pm.z, pl.z);
                split3(a[3], ph.w, pm.w, pl.w);
                size_t base = ((size_t)h * NPT + n) * HD + d0;
                *(ushort4*)(O3 + base)           = ph;
                *(ushort4*)(O3 + OPL + base)     = pm;
                *(ushort4*)(O3 + 2 * OPL + base) = pl;
            }
        }
}

// ---------------------------------------------------------------------------
// 4) masked argmax via bf16x3 MFMA. K tiles (32k x 64d x 3p = 12 KB) LDS
//    double-buffered, prefetch issued before the MFMA burst. Q fragments
//    persistent in regs per head. A = K (m=k), B = Q (n=q).
//    Block: 4 waves x 64q = 256q; k-range 128 per block.
// ---------------------------------------------------------------------------
__global__ __launch_bounds__(256, 2) void score_mfma(const unsigned short* __restrict__ Q3,
                                                     const unsigned short* __restrict__ K3,
                                                     const unsigned* __restrict__ bits,
                                                     float* __restrict__ pval,
                                                     int* __restrict__ pidx) {
    const int qb  = blockIdx.x * 256;        // x = q (consecutive blocks share K slice)
    const int ks  = blockIdx.y;              // 0..KSPLIT-1, KRANGE=128
    const int tid = threadIdx.x;
    const int lane = tid & 63;
    const int m    = lane & 15;
    const int quad = lane >> 4;
    const size_t PL = (size_t)NH * NPT * HD;
    const int kq = qb + (tid >> 6) * 64;

    __shared__ unsigned short Ks[2][3][32][72];   // 64 data + 8 pad per k-row

    const int sk = tid >> 3, sh = (tid & 7) * 8;  // staging coords
    int4 sreg[3];
    auto load_tile = [&](int h, int kst) {
#pragma unroll
        for (int p = 0; p < 3; ++p)
            sreg[p] = *(const int4*)(K3 + (size_t)p * PL
                + ((size_t)h * NPT + ks * 128 + kst * 32 + sk) * HD + sh);
    };
    auto write_tile = [&](int buf) {
#pragma unroll
        for (int p = 0; p < 3; ++p)
            *(int4*)&Ks[buf][p][sk][sh] = sreg[p];
    };

    load_tile(0, 0); write_tile(0);          // prologue: tile (h0,kst0) -> buf 0

#pragma unroll 1
    for (int h = 0; h < NH; ++h) {
        // persistent Q fragments (B-layout: n=lane&15, k=quad*8+j)
        bf16x8 qf[4][2][3];
#pragma unroll
        for (int nt = 0; nt < 4; ++nt)
#pragma unroll
            for (int dc = 0; dc < 2; ++dc)
#pragma unroll
                for (int p = 0; p < 3; ++p)
                    qf[nt][dc][p] = *(const bf16x8*)(Q3 + (size_t)p * PL
                        + ((size_t)h * NPT + kq + nt * 16 + m) * HD + dc * 32 + quad * 8);

        float bestv[4]; int besti[4];
#pragma unroll
        for (int nt = 0; nt < 4; ++nt) { bestv[nt] = -FLT_MAX; besti[nt] = 0; }

#pragma unroll
        for (int kst = 0; kst < 4; ++kst) {
            const int buf = kst & 1;
            const int kbase = ks * 128 + kst * 32;
            const bool last = (h == NH - 1) && (kst == 3);

            __syncthreads();                 // buf now staged & visible

            // current-tile fragments from LDS
            bf16x8 kf[2][2][3];
#pragma unroll
            for (int mt = 0; mt < 2; ++mt)
#pragma unroll
                for (int dc = 0; dc < 2; ++dc)
#pragma unroll
                    for (int p = 0; p < 3; ++p)
                        kf[mt][dc][p] = *(const bf16x8*)
                            &Ks[buf][p][mt * 16 + m][dc * 32 + quad * 8];

            // issue next tile's global loads EARLY (land during MFMA burst)
            if (!last) load_tile(kst < 3 ? h : h + 1, (kst + 1) & 3);

            // bits words for this kst (issued before MFMAs, used after)
            unsigned bw[4];
#pragma unroll
            for (int nt = 0; nt < 4; ++nt)
                bw[nt] = bits[(size_t)(kq + nt * 16 + m) * (NPT / 32) + (kbase >> 5)];

            // MFMA burst, product-major (8 independent acc chains)
            f32x4 acc[2][4];
#pragma unroll
            for (int mt = 0; mt < 2; ++mt)
#pragma unroll
                for (int nt = 0; nt < 4; ++nt) acc[mt][nt] = (f32x4){0.f, 0.f, 0.f, 0.f};
#pragma unroll
            for (int pp = 0; pp < 6; ++pp)
#pragma unroll
                for (int dc = 0; dc < 2; ++dc)
#pragma unroll
                    for (int mt = 0; mt < 2; ++mt)
#pragma unroll
                        for (int nt = 0; nt < 4; ++nt)
                            acc[mt][nt] = __builtin_amdgcn_mfma_f32_16x16x32_bf16(
                                kf[mt][dc][PPA[pp]], qf[nt][dc][PPB[pp]], acc[mt][nt], 0, 0, 0);

            // epilogue: C col=lane&15 -> q; row=quad*4+r -> k
#pragma unroll
            for (int nt = 0; nt < 4; ++nt) {
                unsigned w = bw[nt];
#pragma unroll
                for (int mt = 0; mt < 2; ++mt) {
                    int k0 = mt * 16 + quad * 4;
                    f32x4 a = acc[mt][nt];
#pragma unroll
                    for (int r = 0; r < 4; ++r) {
                        if ((w >> (k0 + r)) & 1u) {
                            float s = a[r];
                            if (s > bestv[nt]) { bestv[nt] = s; besti[nt] = kbase + k0 + r; }
                        }
                    }
                }
            }

            // stage next tile into the other buffer (loads had the whole burst)
            if (!last) write_tile(buf ^ 1);
        }

        // reduce across quad groups; smaller idx on tie
#pragma unroll
        for (int nt = 0; nt < 4; ++nt) {
            float v = bestv[nt]; int bi = besti[nt];
#pragma unroll
            for (int off = 16; off < 64; off <<= 1) {
                float ov = __shfl_xor(v, off);
                int   oi = __shfl_xor(bi, off);
                if (ov > v || (ov == v && oi < bi)) { v = ov; bi = oi; }
            }
            if (quad == 0) {
                size_t o = ((size_t)h * KSPLIT + ks) * NPT + kq + nt * 16 + m;
                pval[o] = v; pidx[o] = bi;
            }
        }
    }
}

// ---------------------------------------------------------------------------
// 5) reduce k-split partials, gather winner V row * (1/NH)
// ---------------------------------------------------------------------------
__global__ __launch_bounds__(128) void gather_out(const float* __restrict__ V,
                                                  const float* __restrict__ pval,
                                                  const int* __restrict__ pidx,
                                                  float* __restrict__ out) {
    const int q = blockIdx.x;
    const int tid = threadIdx.x;
    __shared__ int widx[NH];
    if (tid < NH) {
        float bv = -FLT_MAX; int bi = 0;
        for (int ks = 0; ks < KSPLIT; ++ks) {
            size_t off = ((size_t)tid * KSPLIT + ks) * NPT + q;
            float v = pval[off];
            if (v > bv) { bv = v; bi = pidx[off]; }
        }
        widx[tid] = bi;
    }
    __syncthreads();
    const int h = tid >> 4;
    const int d4 = (tid & 15) * 4;
    const int k = widx[h];
    float4 v = *(const float4*)(V + (size_t)k * EMB + h * HD + d4);
    v.x *= 0.125f; v.y *= 0.125f; v.z *= 0.125f; v.w *= 0.125f;
    *(float4*)(out + (size_t)q * EMB + h * HD + d4) = v;
}

// ---------------------------------------------------------------------------
extern "C" void kernel_launch(void* const* d_in, const int* in_sizes, int n_in,
                              void* d_out, int out_size, void* d_ws, size_t ws_size,
                              hipStream_t stream) {
    const float* x   = (const float*)d_in[0];
    const int*   adj = (const int*)d_in[1];
    const float* WQ  = (const float*)d_in[2];
    const float* WK  = (const float*)d_in[3];
    const float* WV  = (const float*)d_in[4];
    // we/be are dead: energy is constant along k -> argmax unchanged.
    float* out = (float*)d_out;

    char* ws = (char*)d_ws;
    const size_t MB = 1u << 20;
    unsigned short* xs   = (unsigned short*)(ws);                      // 12 MB (dead after gemm)
    unsigned short* wqs  = (unsigned short*)(ws + 12 * MB);            // 1.5 MB
    unsigned short* wks  = (unsigned short*)(ws + 13 * MB + 512 * 1024);
    unsigned short* wvs  = (unsigned short*)(ws + 15 * MB);
    unsigned short* Q3   = (unsigned short*)(ws + 17 * MB);            // 12 MB [3][8][4096][64]
    unsigned short* K3   = (unsigned short*)(ws + 29 * MB);            // 12 MB
    float*          V    = (float*)(ws + 41 * MB);                     // 8 MB [4096][512]
    unsigned*       bits = (unsigned*)(ws + 49 * MB);                  // 2 MB
    float*          pval = (float*)(ws);                               // 4 MB, aliases dead xs
    int*            pidx = (int*)(ws + 4 * MB);                        // 4 MB, aliases dead xs

    pack_adj_kernel<<<dim3(NPT * 128 / 256), dim3(256), 0, stream>>>(adj, bits);
    split_planes<<<dim3(2048, 4), dim3(256), 0, stream>>>(x, WQ, WK, WV, xs, wqs, wks, wvs);
    gemm_mfma<<<dim3(NPT / 128, EMB / 64, 3), dim3(256), 0, stream>>>(xs, wqs, wks, wvs, Q3, K3, V);
    score_mfma<<<dim3(NPT / 256, KSPLIT), dim3(256), 0, stream>>>(Q3, K3, bits, pval, pidx);
    gather_out<<<dim3(NPT), dim3(128), 0, stream>>>(V, pval, pidx, out);
}

// Round 8
// 293.178 us; speedup vs baseline: 9.1787x; 1.3576x over previous
//
#include <hip/hip_runtime.h>
#include <hip/hip_bf16.h>
#include <float.h>
#include <stdint.h>

#define NPT    4096
#define EMB    512
#define NH     8
#define HD     64
#define KSPLIT 32     // score k-range split: KRANGE = 128 (4 tiles of 32)

typedef __attribute__((ext_vector_type(8))) short bf16x8;
typedef __attribute__((ext_vector_type(4))) float f32x4;
typedef uint32_t u32;

// async global->LDS DMA, 16B/lane. LDS dest = ldst + lane*16 (wave-uniform base).
// No VGPR round-trip => no spill pressure (R7 lesson: held staging regs spilled,
// WRITE_SIZE 215 MB).
__device__ __forceinline__ void async_ld16(const void* gsrc, void* ldst) {
    __builtin_amdgcn_global_load_lds(
        (const __attribute__((address_space(1))) u32*)gsrc,
        (__attribute__((address_space(3))) u32*)ldst, 16, 0, 0);
}

// exact 3-way bf16 split of f32 (hi+mid+lo covers all 24 mantissa bits)
__device__ __forceinline__ void split3(float a, unsigned short& h,
                                       unsigned short& m, unsigned short& l) {
    __hip_bfloat16 bh = __float2bfloat16(a);
    float fh = __bfloat162float(bh);
    float r1 = a - fh;
    __hip_bfloat16 bm = __float2bfloat16(r1);
    float fm = __bfloat162float(bm);
    float r2 = r1 - fm;
    __hip_bfloat16 bl = __float2bfloat16(r2);
    h = *reinterpret_cast<unsigned short*>(&bh);
    m = *reinterpret_cast<unsigned short*>(&bm);
    l = *reinterpret_cast<unsigned short*>(&bl);
}

// ---------------------------------------------------------------------------
// 1) pack adj into bitmask [N][N/32]
// ---------------------------------------------------------------------------
__global__ __launch_bounds__(256) void pack_adj_kernel(const int* __restrict__ adj,
                                                       unsigned* __restrict__ bits) {
    int gid = blockIdx.x * 256 + threadIdx.x;
    int q = gid >> 7;
    int w = gid & 127;
    const int4* p = (const int4*)(adj + (size_t)q * NPT + w * 32);
    unsigned m = 0;
#pragma unroll
    for (int i = 0; i < 8; ++i) {
        int4 v = p[i];
        m |= (v.x != 0 ? 1u : 0u) << (i * 4 + 0);
        m |= (v.y != 0 ? 1u : 0u) << (i * 4 + 1);
        m |= (v.z != 0 ? 1u : 0u) << (i * 4 + 2);
        m |= (v.w != 0 ? 1u : 0u) << (i * 4 + 3);
    }
    bits[gid] = m;
}

// ---------------------------------------------------------------------------
// 2) split into 3 bf16 planes. x -> flat [p][n][k]. W -> granule-major tiles
//    [p][ebk(8)][kc(16)][g(4)][e_local(64)][8 shorts] so gemm can stage via
//    contiguous global_load_lds with conflict-free unpadded LDS reads.
// ---------------------------------------------------------------------------
__global__ __launch_bounds__(256) void split_planes(const float* __restrict__ x,
                                                    const float* __restrict__ wq,
                                                    const float* __restrict__ wk,
                                                    const float* __restrict__ wv,
                                                    unsigned short* __restrict__ xs,
                                                    unsigned short* __restrict__ wqs,
                                                    unsigned short* __restrict__ wks,
                                                    unsigned short* __restrict__ wvs) {
    int y = blockIdx.y;
    size_t i = (size_t)blockIdx.x * 256 + threadIdx.x;
    if (y == 0) {
        const size_t PL = (size_t)NPT * EMB;            // 2,097,152
        float4 v = ((const float4*)x)[i];               // i < PL/4 = 524288
        ushort4 h, m, l;
        split3(v.x, h.x, m.x, l.x);
        split3(v.y, h.y, m.y, l.y);
        split3(v.z, h.z, m.z, l.z);
        split3(v.w, h.w, m.w, l.w);
        ((ushort4*)xs)[i]            = h;
        ((ushort4*)(xs + PL))[i]     = m;
        ((ushort4*)(xs + 2 * PL))[i] = l;
    } else {
        const size_t WPL = 262144;                      // per-plane shorts
        if (i >= WPL / 4) return;
        const float* src = (y == 1) ? wq : (y == 2) ? wk : wv;
        unsigned short* dst = (y == 1) ? wqs : (y == 2) ? wks : wvs;
        float4 v = ((const float4*)src)[i];
        int e  = (int)(i >> 7);                         // 128 float4 per 512-k row
        int k0 = ((int)i & 127) * 4;
        int ebk = e >> 6, el = e & 63;
        int kc = k0 >> 5, g = (k0 >> 3) & 3, dd = k0 & 7;   // dd in {0,4}
        size_t off = ((((size_t)ebk * 16 + kc) * 4 + g) * 64 + el) * 8 + dd;
        ushort4 h, m, l;
        split3(v.x, h.x, m.x, l.x);
        split3(v.y, h.y, m.y, l.y);
        split3(v.z, h.z, m.z, l.z);
        split3(v.w, h.w, m.w, l.w);
        *(ushort4*)(dst + off)           = h;
        *(ushort4*)(dst + WPL + off)     = m;
        *(ushort4*)(dst + 2 * WPL + off) = l;
    }
}

// ---------------------------------------------------------------------------
// 3) projections via split-bf16 MFMA. D[e][n] = sum_k W[e][k] x[n][k].
//    Block 64e x 128n, 4 waves (wave owns 32 n). W tile (64e x 32k x 3p =
//    12 KB) double-buffered via global_load_lds; x frags reg-ping-ponged.
//    One barrier per kc tile. z=0 Q3 flat; z=1 K3 granule-major; z=2 V f32.
// ---------------------------------------------------------------------------
__global__ __launch_bounds__(256) void gemm_mfma(const unsigned short* __restrict__ xs,
                                                 const unsigned short* __restrict__ wqs,
                                                 const unsigned short* __restrict__ wks,
                                                 const unsigned short* __restrict__ wvs,
                                                 unsigned short* __restrict__ Q3,
                                                 unsigned short* __restrict__ K3,
                                                 float* __restrict__ V) {
    const int z = blockIdx.z;
    const unsigned short* W3 = (z == 0) ? wqs : (z == 1) ? wks : wvs;
    const size_t XPL = (size_t)NPT * EMB;
    const size_t WPL = 262144;
    const size_t OPL = (size_t)NH * NPT * HD;

    const int nb = blockIdx.x * 128;
    const int ebk = blockIdx.y;            // e-block == head index
    const int tid = threadIdx.x;
    const int wv = tid >> 6, lane = tid & 63;
    const int m = lane & 15, quad = lane >> 4;
    const int n0 = nb + wv * 32;

    __shared__ __align__(16) unsigned short Ws[2][3 * 2048];   // 2 x 12 KB

    auto prefetchW = [&](int kc, int buf) {
#pragma unroll
        for (int i2 = 0; i2 < 3; ++i2) {
            int c = wv + 4 * i2;           // 12 chunks of 1 KB
            int p = c >> 2, sub = c & 3;
            const unsigned short* src = W3 + (size_t)p * WPL
                + ((size_t)ebk * 16 + kc) * 2048 + (sub * 64 + lane) * 8;
            async_ld16(src, &Ws[buf][p * 2048 + sub * 512]);
        }
    };
    bf16x8 bfA[2][3], bfB[2][3];
    auto load_bf = [&](bf16x8 (&bf)[2][3], int kc) {
#pragma unroll
        for (int nt = 0; nt < 2; ++nt)
#pragma unroll
            for (int p = 0; p < 3; ++p)
                bf[nt][p] = *(const bf16x8*)(xs + (size_t)p * XPL
                    + (size_t)(n0 + nt * 16 + m) * EMB + kc * 32 + quad * 8);
    };

    f32x4 acc[4][2];
#pragma unroll
    for (int mt = 0; mt < 4; ++mt)
#pragma unroll
        for (int nt = 0; nt < 2; ++nt) acc[mt][nt] = (f32x4){0.f, 0.f, 0.f, 0.f};

    prefetchW(0, 0);
    load_bf(bfA, 0);

    auto iter = [&](int kc, int buf, bf16x8 (&cur)[2][3], bf16x8 (&nxt)[2][3]) {
        __syncthreads();                   // publishes Ws[buf]; readers of buf^1 done
        if (kc < 15) { prefetchW(kc + 1, buf ^ 1); load_bf(nxt, kc + 1); }
        // products (A-plane, B-plane): (0,0)(0,1)(0,2)(1,0)(1,1)(2,0) = exact set
#pragma unroll
        for (int ga = 0; ga < 3; ++ga) {
            bf16x8 af[4];
#pragma unroll
            for (int mt = 0; mt < 4; ++mt)
                af[mt] = *(const bf16x8*)&Ws[buf][ga * 2048 + (quad * 64 + mt * 16 + m) * 8];
#pragma unroll
            for (int pb = 0; pb < 3 - ga; ++pb)
#pragma unroll
                for (int mt = 0; mt < 4; ++mt)
#pragma unroll
                    for (int nt = 0; nt < 2; ++nt)
                        acc[mt][nt] = __builtin_amdgcn_mfma_f32_16x16x32_bf16(
                            af[mt], cur[nt][pb], acc[mt][nt], 0, 0, 0);
        }
    };

#pragma unroll 1
    for (int kc2 = 0; kc2 < 16; kc2 += 2) {
        iter(kc2, 0, bfA, bfB);
        iter(kc2 + 1, 1, bfB, bfA);
    }

    // C/D: col(lane&15)=n, row(quad*4+r)=e
    const int h = ebk;
#pragma unroll
    for (int mt = 0; mt < 4; ++mt)
#pragma unroll
        for (int nt = 0; nt < 2; ++nt) {
            const int n = n0 + nt * 16 + m;
            const int d0 = mt * 16 + quad * 4;
            f32x4 a = acc[mt][nt];
            if (z == 2) {
                *(f32x4*)(V + (size_t)n * EMB + ebk * 64 + d0) = a;
            } else {
                ushort4 ph, pm, pl;
                split3(a[0], ph.x, pm.x, pl.x);
                split3(a[1], ph.y, pm.y, pl.y);
                split3(a[2], ph.z, pm.z, pl.z);
                split3(a[3], ph.w, pm.w, pl.w);
                if (z == 0) {              // Q3 flat [p][h][n][d]
                    size_t base = ((size_t)h * NPT + n) * HD + d0;
                    *(ushort4*)(Q3 + base)           = ph;
                    *(ushort4*)(Q3 + OPL + base)     = pm;
                    *(ushort4*)(Q3 + 2 * OPL + base) = pl;
                } else {                   // K3 granule-major [p][h][kt][g][kk][8]
                    int kt = n >> 5, kk = n & 31, g = d0 >> 3, dd = d0 & 7;
                    size_t off = ((size_t)h * 128 + kt) * 2048 + g * 256 + kk * 8 + dd;
                    *(ushort4*)(K3 + off)           = ph;
                    *(ushort4*)(K3 + OPL + off)     = pm;
                    *(ushort4*)(K3 + 2 * OPL + off) = pl;
                }
            }
        }
}

// ---------------------------------------------------------------------------
// 4) masked argmax via bf16x3 MFMA. K tile (32k x 64d x 3p = 12 KB) staged
//    granule-major via global_load_lds, double-buffered, 1 barrier/tile.
//    Block: 4 waves x 32q = 128q; k-range 128 (4 tiles). A=K, B=Q.
// ---------------------------------------------------------------------------
__global__ __launch_bounds__(256) void score_mfma(const unsigned short* __restrict__ Q3,
                                                  const unsigned short* __restrict__ K3,
                                                  const unsigned* __restrict__ bits,
                                                  float* __restrict__ pval,
                                                  int* __restrict__ pidx) {
    const int qb = blockIdx.x * 128;       // x fastest: 32 consecutive blocks share K slice
    const int ks = blockIdx.y;
    const int tid = threadIdx.x;
    const int wv = tid >> 6, lane = tid & 63;
    const int m = lane & 15, quad = lane >> 4;
    const size_t PL = (size_t)NH * NPT * HD;
    const int kq = qb + wv * 32;

    __shared__ __align__(16) unsigned short Ks[2][3 * 2048];   // 2 x 12 KB

    auto prefetchK = [&](int h, int kst, int buf) {
        int kt = ks * 4 + kst;
#pragma unroll
        for (int i2 = 0; i2 < 3; ++i2) {
            int c = wv + 4 * i2;
            int p = c >> 2, sub = c & 3;
            const unsigned short* src = K3 + (size_t)p * PL
                + ((size_t)h * 128 + kt) * 2048 + (sub * 64 + lane) * 8;
            async_ld16(src, &Ks[buf][p * 2048 + sub * 512]);
        }
    };

    prefetchK(0, 0, 0);

    bf16x8 qf[2][2][3];
    float bestv[2]; int besti[2];

#pragma unroll 1
    for (int h = 0; h < NH; ++h) {
#pragma unroll
        for (int kst = 0; kst < 4; ++kst) {
            const int buf = kst & 1;
            const int kbase = (ks * 4 + kst) * 32;
            __syncthreads();               // Ks[buf] staged & visible; buf^1 readers done
            if (kst < 3)            prefetchK(h, kst + 1, buf ^ 1);
            else if (h < NH - 1)    prefetchK(h + 1, 0, buf ^ 1);

            if (kst == 0) {                // per-head Q fragments (B: n=lane&15, k=quad*8+j)
#pragma unroll
                for (int nt = 0; nt < 2; ++nt)
#pragma unroll
                    for (int dc = 0; dc < 2; ++dc)
#pragma unroll
                        for (int p = 0; p < 3; ++p)
                            qf[nt][dc][p] = *(const bf16x8*)(Q3 + (size_t)p * PL
                                + ((size_t)h * NPT + kq + nt * 16 + m) * HD + dc * 32 + quad * 8);
                bestv[0] = bestv[1] = -FLT_MAX;
                besti[0] = besti[1] = 0;
            }

            unsigned bw[2];
#pragma unroll
            for (int nt = 0; nt < 2; ++nt)
                bw[nt] = bits[(size_t)(kq + nt * 16 + m) * (NPT / 32) + (kbase >> 5)];

            f32x4 acc[2][2];
#pragma unroll
            for (int mt = 0; mt < 2; ++mt)
#pragma unroll
                for (int nt = 0; nt < 2; ++nt) acc[mt][nt] = (f32x4){0.f, 0.f, 0.f, 0.f};

            // A-plane-grouped products: kf live = 16 VGPRs only
#pragma unroll
            for (int ga = 0; ga < 3; ++ga) {
                bf16x8 kf[2][2];
#pragma unroll
                for (int mt = 0; mt < 2; ++mt)
#pragma unroll
                    for (int dc = 0; dc < 2; ++dc)
                        kf[mt][dc] = *(const bf16x8*)
                            &Ks[buf][ga * 2048 + ((dc * 4 + quad) * 32 + mt * 16 + m) * 8];
#pragma unroll
                for (int pb = 0; pb < 3 - ga; ++pb)
#pragma unroll
                    for (int dc = 0; dc < 2; ++dc)
#pragma unroll
                        for (int mt = 0; mt < 2; ++mt)
#pragma unroll
                            for (int nt = 0; nt < 2; ++nt)
                                acc[mt][nt] = __builtin_amdgcn_mfma_f32_16x16x32_bf16(
                                    kf[mt][dc], qf[nt][dc][pb], acc[mt][nt], 0, 0, 0);
            }

            // C: col=lane&15 -> q; row=quad*4+r -> k
#pragma unroll
            for (int nt = 0; nt < 2; ++nt) {
                unsigned w = bw[nt];
#pragma unroll
                for (int mt = 0; mt < 2; ++mt) {
                    int k0 = mt * 16 + quad * 4;
                    f32x4 a = acc[mt][nt];
#pragma unroll
                    for (int r = 0; r < 4; ++r) {
                        if ((w >> (k0 + r)) & 1u) {
                            float s = a[r];
                            if (s > bestv[nt]) { bestv[nt] = s; besti[nt] = kbase + k0 + r; }
                        }
                    }
                }
            }

            if (kst == 3) {                // end of head: reduce over quad groups
#pragma unroll
                for (int nt = 0; nt < 2; ++nt) {
                    float v = bestv[nt]; int bi = besti[nt];
#pragma unroll
                    for (int off = 16; off < 64; off <<= 1) {
                        float ov = __shfl_xor(v, off);
                        int   oi = __shfl_xor(bi, off);
                        if (ov > v || (ov == v && oi < bi)) { v = ov; bi = oi; }
                    }
                    if (quad == 0) {
                        size_t o = ((size_t)h * KSPLIT + ks) * NPT + kq + nt * 16 + m;
                        pval[o] = v; pidx[o] = bi;
                    }
                }
            }
        }
    }
}

// ---------------------------------------------------------------------------
// 5) reduce k-split partials, gather winner V row * (1/NH)
// ---------------------------------------------------------------------------
__global__ __launch_bounds__(128) void gather_out(const float* __restrict__ V,
                                                  const float* __restrict__ pval,
                                                  const int* __restrict__ pidx,
                                                  float* __restrict__ out) {
    const int q = blockIdx.x;
    const int tid = threadIdx.x;
    __shared__ int widx[NH];
    if (tid < NH) {
        float bv = -FLT_MAX; int bi = 0;
        for (int ks = 0; ks < KSPLIT; ++ks) {
            size_t off = ((size_t)tid * KSPLIT + ks) * NPT + q;
            float v = pval[off];
            if (v > bv) { bv = v; bi = pidx[off]; }
        }
        widx[tid] = bi;
    }
    __syncthreads();
    const int h = tid >> 4;
    const int d4 = (tid & 15) * 4;
    const int k = widx[h];
    float4 v = *(const float4*)(V + (size_t)k * EMB + h * HD + d4);
    v.x *= 0.125f; v.y *= 0.125f; v.z *= 0.125f; v.w *= 0.125f;
    *(float4*)(out + (size_t)q * EMB + h * HD + d4) = v;
}

// ---------------------------------------------------------------------------
extern "C" void kernel_launch(void* const* d_in, const int* in_sizes, int n_in,
                              void* d_out, int out_size, void* d_ws, size_t ws_size,
                              hipStream_t stream) {
    const float* x   = (const float*)d_in[0];
    const int*   adj = (const int*)d_in[1];
    const float* WQ  = (const float*)d_in[2];
    const float* WK  = (const float*)d_in[3];
    const float* WV  = (const float*)d_in[4];
    // we/be are dead: energy is constant along k -> argmax unchanged.
    float* out = (float*)d_out;

    char* ws = (char*)d_ws;
    const size_t HMB = 512u * 1024;     // 0.5 MB unit
    unsigned short* xs   = (unsigned short*)(ws);                 // 12 MB (dead after gemm)
    unsigned short* wqs  = (unsigned short*)(ws + 24 * HMB);      // 1.5 MB each
    unsigned short* wks  = (unsigned short*)(ws + 27 * HMB);
    unsigned short* wvs  = (unsigned short*)(ws + 30 * HMB);
    unsigned short* Q3   = (unsigned short*)(ws + 33 * HMB);      // 12 MB flat
    unsigned short* K3   = (unsigned short*)(ws + 57 * HMB);      // 12 MB granule-major
    float*          V    = (float*)(ws + 81 * HMB);               // 8 MB
    unsigned*       bits = (unsigned*)(ws + 97 * HMB);            // 2 MB  (total 50.5 MB)
    float*          pval = (float*)(ws);                          // 4 MB, aliases dead xs
    int*            pidx = (int*)(ws + 8 * HMB);                  // 4 MB, aliases dead xs

    pack_adj_kernel<<<dim3(NPT * 128 / 256), dim3(256), 0, stream>>>(adj, bits);
    split_planes<<<dim3(2048, 4), dim3(256), 0, stream>>>(x, WQ, WK, WV, xs, wqs, wks, wvs);
    gemm_mfma<<<dim3(NPT / 128, NH, 3), dim3(256), 0, stream>>>(xs, wqs, wks, wvs, Q3, K3, V);
    score_mfma<<<dim3(NPT / 128, KSPLIT), dim3(256), 0, stream>>>(Q3, K3, bits, pval, pidx);
    gather_out<<<dim3(NPT), dim3(128), 0, stream>>>(V, pval, pidx, out);
}